// Round 1
// baseline (462.296 us; speedup 1.0000x reference)
//
#include <hip/hip_runtime.h>
#include <math.h>

#define CCLS 16
#define BB   2048
#define NBT  32   // BB / 64 b-tiles

// ---------------------------------------------------------------------------
// Tiled fp32 GEMM:  Out[c,b,o] = sum_k A[c,b,k] * W[c,o,k] + bias[c,o]
// Optionally applies BN+ReLU to A on load:  a' = max(0, a*scale[c,k]+shift[c,k])
// Optionally emits per-(c,o,btile) partial sums / sums-of-squares of the output
// (deterministic two-phase BN stats — no float atomics).
// Tile: 64 (rows b) x 64 (cols o) x 32 (k). 256 threads, 4x4 per thread.
// ---------------------------------------------------------------------------
template<bool FUSE_BN, bool WRITE_STATS>
__global__ __launch_bounds__(256)
void gemm_bn_kernel(const float* __restrict__ A,      // [C][BB][K]   (raw, pre-BN)
                    const float* __restrict__ W,      // [C][Fout][K]
                    const float* __restrict__ bias,   // [C][Fout]
                    const float* __restrict__ scale,  // [C][K]  (if FUSE_BN)
                    const float* __restrict__ shift,  // [C][K]
                    float* __restrict__ Out,          // [C][BB][Fout]
                    float* __restrict__ psum,         // [C][Fout][NBT] (if WRITE_STATS)
                    float* __restrict__ psq,
                    int K, int Fout)
{
    __shared__ float As[64][36];   // +4 pad: 16B-aligned float4 rows, mild bank spread
    __shared__ float Ws[64][36];
    __shared__ float sc_s[512];
    __shared__ float sh_s[512];

    const int tid = threadIdx.x;
    const int tx  = tid & 15;       // output col group
    const int ty  = tid >> 4;       // output row group
    const int btile = blockIdx.x, otile = blockIdx.y, c = blockIdx.z;
    const int b0 = btile * 64, o0 = otile * 64;

    const float* Ac = A + (size_t)c * BB * K;
    const float* Wc = W + (size_t)c * Fout * K;

    if (FUSE_BN) {
        for (int i = tid; i < K; i += 256) {
            sc_s[i] = scale[c * K + i];
            sh_s[i] = shift[c * K + i];
        }
    }

    float acc[4][4] = {};

    const int r  = tid >> 3;         // 0..31  (tile row for loading)
    const int kq = (tid & 7) << 2;   // 0,4,...,28 (k quad)

    for (int k0 = 0; k0 < K; k0 += 32) {
        __syncthreads();   // protects prev iter's reads AND sc_s preload (1st iter)
        const int gk = k0 + kq;
        #pragma unroll
        for (int half = 0; half < 2; ++half) {
            const int row = r + half * 32;
            // ---- A tile (apply BN+ReLU on load if fused) ----
            {
                const float* ap = Ac + (size_t)(b0 + row) * K + gk;
                float4 v;
                if (gk + 3 < K) {
                    v = *(const float4*)ap;
                    if (FUSE_BN) {
                        v.x = fmaxf(0.f, fmaf(v.x, sc_s[gk + 0], sh_s[gk + 0]));
                        v.y = fmaxf(0.f, fmaf(v.y, sc_s[gk + 1], sh_s[gk + 1]));
                        v.z = fmaxf(0.f, fmaf(v.z, sc_s[gk + 2], sh_s[gk + 2]));
                        v.w = fmaxf(0.f, fmaf(v.w, sc_s[gk + 3], sh_s[gk + 3]));
                    }
                } else {  // K tail (only layer 1, K=100, no BN)
                    float e[4];
                    #pragma unroll
                    for (int j = 0; j < 4; ++j) {
                        float t = (gk + j < K) ? ap[j] : 0.f;
                        if (FUSE_BN && gk + j < K)
                            t = fmaxf(0.f, fmaf(t, sc_s[gk + j], sh_s[gk + j]));
                        e[j] = t;
                    }
                    v.x = e[0]; v.y = e[1]; v.z = e[2]; v.w = e[3];
                }
                *(float4*)&As[row][kq] = v;
            }
            // ---- W tile ----
            {
                const float* wp = Wc + (size_t)(o0 + row) * K + gk;
                float4 v;
                if (gk + 3 < K) {
                    v = *(const float4*)wp;
                } else {
                    v.x = (gk + 0 < K) ? wp[0] : 0.f;
                    v.y = (gk + 1 < K) ? wp[1] : 0.f;
                    v.z = (gk + 2 < K) ? wp[2] : 0.f;
                    v.w = (gk + 3 < K) ? wp[3] : 0.f;
                }
                *(float4*)&Ws[row][kq] = v;
            }
        }
        __syncthreads();

        #pragma unroll
        for (int kk = 0; kk < 32; kk += 4) {
            float4 a[4], w[4];
            #pragma unroll
            for (int m = 0; m < 4; ++m) a[m] = *(const float4*)&As[ty + 16 * m][kk];
            #pragma unroll
            for (int n = 0; n < 4; ++n) w[n] = *(const float4*)&Ws[tx + 16 * n][kk];
            #pragma unroll
            for (int m = 0; m < 4; ++m)
                #pragma unroll
                for (int n = 0; n < 4; ++n) {
                    acc[m][n] = fmaf(a[m].x, w[n].x, acc[m][n]);
                    acc[m][n] = fmaf(a[m].y, w[n].y, acc[m][n]);
                    acc[m][n] = fmaf(a[m].z, w[n].z, acc[m][n]);
                    acc[m][n] = fmaf(a[m].w, w[n].w, acc[m][n]);
                }
        }
    }

    // ---- epilogue: bias, store, per-tile BN partial stats ----
    float bv[4];
    #pragma unroll
    for (int n = 0; n < 4; ++n) bv[n] = bias[c * Fout + o0 + tx + 16 * n];

    float p[4] = {}, q[4] = {};
    #pragma unroll
    for (int m = 0; m < 4; ++m) {
        const int row = b0 + ty + 16 * m;
        float* op = Out + ((size_t)c * BB + row) * Fout + o0;
        #pragma unroll
        for (int n = 0; n < 4; ++n) {
            const float v = acc[m][n] + bv[n];
            op[tx + 16 * n] = v;
            if (WRITE_STATS) { p[n] += v; q[n] += v * v; }
        }
    }

    if (WRITE_STATS) {
        __syncthreads();                    // done reading As/Ws — reuse as scratch
        float* redP = &As[0][0];            // [16][64]
        float* redQ = &Ws[0][0];
        #pragma unroll
        for (int n = 0; n < 4; ++n) {
            redP[ty * 64 + tx + 16 * n] = p[n];
            redQ[ty * 64 + tx + 16 * n] = q[n];
        }
        __syncthreads();
        if (tid < 64) {
            float sp = 0.f, sq = 0.f;
            #pragma unroll
            for (int t = 0; t < 16; ++t) {
                sp += redP[t * 64 + tid];
                sq += redQ[t * 64 + tid];
            }
            const size_t o = ((size_t)c * Fout + o0 + tid) * NBT + btile;
            psum[o] = sp;
            psq[o]  = sq;
        }
    }
}

// Fold NBT partials -> BN scale/shift per (c, feature). Deterministic order.
__global__ __launch_bounds__(256)
void combine_kernel(const float* __restrict__ psum, const float* __restrict__ psq,
                    const float* __restrict__ g, const float* __restrict__ be,
                    float* __restrict__ scale, float* __restrict__ shift, int n)
{
    const int idx = blockIdx.x * 256 + threadIdx.x;
    if (idx >= n) return;
    float s = 0.f, q = 0.f;
    #pragma unroll 8
    for (int t = 0; t < NBT; ++t) { s += psum[idx * NBT + t]; q += psq[idx * NBT + t]; }
    const float mean = s * (1.f / BB);
    const float var  = q * (1.f / BB) - mean * mean;
    const float rstd = rsqrtf(var + 1e-5f);
    const float scv  = g[idx] * rstd;
    scale[idx] = scv;
    shift[idx] = fmaf(-mean, scv, be[idx]);
}

__global__ __launch_bounds__(256)
void label_kernel(float* __restrict__ out)
{
    const int i = blockIdx.x * 256 + threadIdx.x;
    out[i] = (float)(i >> 11);   // i / 2048
}

// ---------------------------------------------------------------------------
extern "C" void kernel_launch(void* const* d_in, const int* in_sizes, int n_in,
                              void* d_out, int out_size, void* d_ws, size_t ws_size,
                              hipStream_t stream)
{
    const float* x = (const float*)d_in[0];
    const float* W[5];  const float* bs[5];
    for (int l = 0; l < 5; ++l) { W[l] = (const float*)d_in[1 + 2 * l]; bs[l] = (const float*)d_in[2 + 2 * l]; }
    const float* g[4];  const float* be[4];
    for (int l = 0; l < 4; ++l) { g[l] = (const float*)d_in[11 + 2 * l]; be[l] = (const float*)d_in[12 + 2 * l]; }

    float* out     = (float*)d_out;
    float* gendata = out;                              // [C*BB, 512] — doubles as h1
    float* label   = out + (size_t)CCLS * BB * 512;

    float* ws   = (float*)d_ws;
    float* h2   = ws;                                  // C*BB*256
    float* h3   = h2 + (size_t)CCLS * BB * 256;        // C*BB*128
    float* h4   = h2;                                  // alias: h2 dead after gemm3
    float* psum = h3 + (size_t)CCLS * BB * 128;        // C*512*NBT
    float* psq  = psum + (size_t)CCLS * 512 * NBT;
    float* scl  = psq  + (size_t)CCLS * 512 * NBT;     // C*512
    float* shf  = scl  + (size_t)CCLS * 512;

    const dim3 blk(256);

    // L1: x[K=100] -> h1(=gendata)[512], stats
    gemm_bn_kernel<false, true><<<dim3(NBT, 8, CCLS), blk, 0, stream>>>(
        x, W[0], bs[0], nullptr, nullptr, gendata, psum, psq, 100, 512);
    combine_kernel<<<dim3(CCLS * 512 / 256), blk, 0, stream>>>(psum, psq, g[0], be[0], scl, shf, CCLS * 512);

    // L2: bn(h1)->relu -> h2[256], stats
    gemm_bn_kernel<true, true><<<dim3(NBT, 4, CCLS), blk, 0, stream>>>(
        gendata, W[1], bs[1], scl, shf, h2, psum, psq, 512, 256);
    combine_kernel<<<dim3(CCLS * 256 / 256), blk, 0, stream>>>(psum, psq, g[1], be[1], scl, shf, CCLS * 256);

    // L3: -> h3[128], stats
    gemm_bn_kernel<true, true><<<dim3(NBT, 2, CCLS), blk, 0, stream>>>(
        h2, W[2], bs[2], scl, shf, h3, psum, psq, 256, 128);
    combine_kernel<<<dim3(CCLS * 128 / 256), blk, 0, stream>>>(psum, psq, g[2], be[2], scl, shf, CCLS * 128);

    // L4: -> h4[256] (aliases h2; h2's last reader was gemm3), stats
    gemm_bn_kernel<true, true><<<dim3(NBT, 4, CCLS), blk, 0, stream>>>(
        h3, W[3], bs[3], scl, shf, h4, psum, psq, 128, 256);
    combine_kernel<<<dim3(CCLS * 256 / 256), blk, 0, stream>>>(psum, psq, g[3], be[3], scl, shf, CCLS * 256);

    // L5: bn(h4)->relu -> gendata[512] (no BN/ReLU after, no stats)
    gemm_bn_kernel<true, false><<<dim3(NBT, 8, CCLS), blk, 0, stream>>>(
        h4, W[4], bs[4], scl, shf, gendata, nullptr, nullptr, 256, 512);

    label_kernel<<<dim3(CCLS * BB / 256), blk, 0, stream>>>(label);
}

// Round 2
// 250.312 us; speedup vs baseline: 1.8469x; 1.8469x over previous
//
#include <hip/hip_runtime.h>
#include <math.h>

#define CCLS 16
#define BB   2048
#define NBT  16   // BB / 128 b-tiles

using bf16x8  = __attribute__((ext_vector_type(8))) short;
using short4v = __attribute__((ext_vector_type(4))) short;
using f32x4   = __attribute__((ext_vector_type(4))) float;

__device__ __forceinline__ short f2bf(float f) {   // round-to-nearest-even bf16
    unsigned u = __builtin_bit_cast(unsigned, f);
    u = u + 0x7fffu + ((u >> 16) & 1u);
    return (short)(u >> 16);
}
__device__ __forceinline__ float bf2f(short s) {
    unsigned u = ((unsigned)(unsigned short)s) << 16;
    return __builtin_bit_cast(float, u);
}
// XOR-swizzled LDS address for [128 rows][32 bf16 = 64B] tile (bijective, spreads
// 8 consecutive rows' same-slot reads across all 32 banks).
__device__ __forceinline__ int swz(int row, int kbyte) {
    return ((row << 6) + kbyte) ^ ((row & 7) << 4);
}

// ---------------------------------------------------------------------------
// MFMA GEMM with fp32 -> bf16 hi/lo split (3-product emulation):
//   Out[c,b,o] = sum_k A'[c,b,k] * W[c,o,k] + bias[c,o]
//   A' = FUSE_BN ? relu(A*scale + shift) : A      (applied during staging)
// Tile: 128(b) x 128(o) x 32(k). 4 waves, each 64x64 via 4x4 mfma_16x16x32_bf16.
// Optional deterministic per-(c,o,btile) partial BN stats of the output.
// ---------------------------------------------------------------------------
template<bool FUSE_BN, bool WRITE_STATS>
__global__ __launch_bounds__(256, 2)
void gemm_mfma_kernel(const float* __restrict__ A,      // [C][BB][K]
                      const float* __restrict__ W,      // [C][Fout][K]
                      const float* __restrict__ bias,   // [C][Fout]
                      const float* __restrict__ scale,  // [C][K] (if FUSE_BN)
                      const float* __restrict__ shift,  // [C][K]
                      float* __restrict__ Out,          // [C][BB][Fout]
                      float* __restrict__ psum,         // [C][Fout][NBT]
                      float* __restrict__ psq,
                      int K, int Fout)
{
    __shared__ __align__(16) char sm[32768];
    char* AHI = sm;            // 8KB: [128][32] bf16, swizzled
    char* ALO = sm + 8192;
    char* WHI = sm + 16384;
    char* WLO = sm + 24576;

    const int tid   = threadIdx.x;
    const int btile = blockIdx.x, otile = blockIdx.y, c = blockIdx.z;
    const int b0 = btile * 128, o0 = otile * 128;

    const float* Ac = A + (size_t)c * BB * K;
    const float* Wc = W + ((size_t)c * Fout + o0) * K;

    // staging map: thread -> (row 0..31 [+32*it], k-quad)
    const int tr  = tid >> 3;
    const int tk4 = (tid & 7) << 2;

    // compute map: 4 waves in 2x2, each owns 64x64
    const int lane = tid & 63;
    const int wv   = tid >> 6;
    const int wrow = (wv >> 1) << 6;
    const int wcol = (wv & 1) << 6;
    const int fr   = lane & 15;          // row (A) / col (B) within 16
    const int fkb  = (lane >> 4) << 4;   // byte offset of this lane's 8 bf16 k-slice

    f32x4 acc[4][4];
    #pragma unroll
    for (int mi = 0; mi < 4; ++mi)
        #pragma unroll
        for (int ni = 0; ni < 4; ++ni)
            acc[mi][ni] = (f32x4){0.f, 0.f, 0.f, 0.f};

    for (int k0 = 0; k0 < K; k0 += 32) {
        __syncthreads();   // previous stage's frag reads done before overwrite
        const int gk = k0 + tk4;

        float sc4[4], sh4[4];
        if (FUSE_BN) {     // K is a multiple of 32 whenever FUSE_BN
            float4 s4 = *(const float4*)(scale + (size_t)c * K + gk);
            float4 t4 = *(const float4*)(shift + (size_t)c * K + gk);
            sc4[0] = s4.x; sc4[1] = s4.y; sc4[2] = s4.z; sc4[3] = s4.w;
            sh4[0] = t4.x; sh4[1] = t4.y; sh4[2] = t4.z; sh4[3] = t4.w;
        }

        // ---- stage A (BN+ReLU fused, fp32 -> hi/lo bf16) ----
        #pragma unroll
        for (int it = 0; it < 4; ++it) {
            const int row = tr + (it << 5);
            const float* ap = Ac + (size_t)(b0 + row) * K + gk;
            float xv[4];
            if (gk + 3 < K) {
                float4 v = *(const float4*)ap;
                xv[0] = v.x; xv[1] = v.y; xv[2] = v.z; xv[3] = v.w;
            } else {
                #pragma unroll
                for (int j = 0; j < 4; ++j) xv[j] = (gk + j < K) ? ap[j] : 0.f;
            }
            short hv[4], lv[4];
            #pragma unroll
            for (int j = 0; j < 4; ++j) {
                if (FUSE_BN) xv[j] = fmaxf(0.f, fmaf(xv[j], sc4[j], sh4[j]));
                hv[j] = f2bf(xv[j]);
                lv[j] = f2bf(xv[j] - bf2f(hv[j]));
            }
            const int off = swz(row, tk4 << 1);
            *(short4v*)(AHI + off) = (short4v){hv[0], hv[1], hv[2], hv[3]};
            *(short4v*)(ALO + off) = (short4v){lv[0], lv[1], lv[2], lv[3]};
        }
        // ---- stage W (fp32 -> hi/lo bf16) ----
        #pragma unroll
        for (int it = 0; it < 4; ++it) {
            const int row = tr + (it << 5);
            const float* wp = Wc + (size_t)row * K + gk;
            float xv[4];
            if (gk + 3 < K) {
                float4 v = *(const float4*)wp;
                xv[0] = v.x; xv[1] = v.y; xv[2] = v.z; xv[3] = v.w;
            } else {
                #pragma unroll
                for (int j = 0; j < 4; ++j) xv[j] = (gk + j < K) ? wp[j] : 0.f;
            }
            short hv[4], lv[4];
            #pragma unroll
            for (int j = 0; j < 4; ++j) {
                hv[j] = f2bf(xv[j]);
                lv[j] = f2bf(xv[j] - bf2f(hv[j]));
            }
            const int off = swz(row, tk4 << 1);
            *(short4v*)(WHI + off) = (short4v){hv[0], hv[1], hv[2], hv[3]};
            *(short4v*)(WLO + off) = (short4v){lv[0], lv[1], lv[2], lv[3]};
        }
        __syncthreads();

        // ---- fragments + 48 MFMA ----
        // A and B use the SAME (lane-group, elem)->k map, so the result is
        // invariant to the HW's internal k permutation (operand symmetry).
        bf16x8 ah[4], al[4], wh[4], wl[4];
        #pragma unroll
        for (int i = 0; i < 4; ++i) {
            const int offA = swz(wrow + (i << 4) + fr, fkb);
            ah[i] = *(const bf16x8*)(AHI + offA);
            al[i] = *(const bf16x8*)(ALO + offA);
            const int offW = swz(wcol + (i << 4) + fr, fkb);
            wh[i] = *(const bf16x8*)(WHI + offW);
            wl[i] = *(const bf16x8*)(WLO + offW);
        }
        #pragma unroll
        for (int mi = 0; mi < 4; ++mi)
            #pragma unroll
            for (int ni = 0; ni < 4; ++ni) {
                acc[mi][ni] = __builtin_amdgcn_mfma_f32_16x16x32_bf16(ah[mi], wh[ni], acc[mi][ni], 0, 0, 0);
                acc[mi][ni] = __builtin_amdgcn_mfma_f32_16x16x32_bf16(ah[mi], wl[ni], acc[mi][ni], 0, 0, 0);
                acc[mi][ni] = __builtin_amdgcn_mfma_f32_16x16x32_bf16(al[mi], wh[ni], acc[mi][ni], 0, 0, 0);
            }
    }

    // ---- epilogue: bias, store, BN partial stats ----
    // C/D layout (verified): col = lane&15, row = (lane>>4)*4 + reg
    float bv[4];
    #pragma unroll
    for (int ni = 0; ni < 4; ++ni)
        bv[ni] = bias[(size_t)c * Fout + o0 + wcol + (ni << 4) + fr];

    float p[4] = {}, q[4] = {};
    const int rsub = (lane >> 4) << 2;
    #pragma unroll
    for (int mi = 0; mi < 4; ++mi) {
        #pragma unroll
        for (int j = 0; j < 4; ++j) {
            const int row = b0 + wrow + (mi << 4) + rsub + j;
            float* op = Out + ((size_t)c * BB + row) * Fout + o0 + wcol;
            #pragma unroll
            for (int ni = 0; ni < 4; ++ni) {
                const float v = acc[mi][ni][j] + bv[ni];
                op[(ni << 4) + fr] = v;
                if (WRITE_STATS) { p[ni] += v; q[ni] += v * v; }
            }
        }
    }

    if (WRITE_STATS) {
        #pragma unroll
        for (int ni = 0; ni < 4; ++ni) {   // fold the 4 row-groups per column
            p[ni] += __shfl_xor(p[ni], 16); p[ni] += __shfl_xor(p[ni], 32);
            q[ni] += __shfl_xor(q[ni], 16); q[ni] += __shfl_xor(q[ni], 32);
        }
        __syncthreads();                   // smem frag reads done — reuse as scratch
        float* redp = (float*)sm;          // [2][128]
        float* redq = (float*)(sm + 1024);
        if (lane < 16) {
            const int base = (wv >> 1) * 128 + wcol;
            #pragma unroll
            for (int ni = 0; ni < 4; ++ni) {
                redp[base + (ni << 4) + fr] = p[ni];
                redq[base + (ni << 4) + fr] = q[ni];
            }
        }
        __syncthreads();
        if (tid < 128) {
            const float sp = redp[tid] + redp[128 + tid];
            const float sq = redq[tid] + redq[128 + tid];
            const size_t o = ((size_t)c * Fout + o0 + tid) * NBT + btile;
            psum[o] = sp;
            psq[o]  = sq;
        }
    }
}

// Fold NBT partials -> BN scale/shift per (c, feature). Deterministic order.
__global__ __launch_bounds__(256)
void combine_kernel(const float* __restrict__ psum, const float* __restrict__ psq,
                    const float* __restrict__ g, const float* __restrict__ be,
                    float* __restrict__ scale, float* __restrict__ shift, int n)
{
    const int idx = blockIdx.x * 256 + threadIdx.x;
    if (idx >= n) return;
    float s = 0.f, q = 0.f;
    #pragma unroll
    for (int t = 0; t < NBT; ++t) { s += psum[idx * NBT + t]; q += psq[idx * NBT + t]; }
    const float mean = s * (1.f / BB);
    const float var  = q * (1.f / BB) - mean * mean;
    const float rstd = rsqrtf(var + 1e-5f);
    const float scv  = g[idx] * rstd;
    scale[idx] = scv;
    shift[idx] = fmaf(-mean, scv, be[idx]);
}

__global__ __launch_bounds__(256)
void label_kernel(float* __restrict__ out)
{
    const int i = blockIdx.x * 256 + threadIdx.x;
    out[i] = (float)(i >> 11);   // i / 2048
}

// ---------------------------------------------------------------------------
extern "C" void kernel_launch(void* const* d_in, const int* in_sizes, int n_in,
                              void* d_out, int out_size, void* d_ws, size_t ws_size,
                              hipStream_t stream)
{
    const float* x = (const float*)d_in[0];
    const float* W[5];  const float* bs[5];
    for (int l = 0; l < 5; ++l) { W[l] = (const float*)d_in[1 + 2 * l]; bs[l] = (const float*)d_in[2 + 2 * l]; }
    const float* g[4];  const float* be[4];
    for (int l = 0; l < 4; ++l) { g[l] = (const float*)d_in[11 + 2 * l]; be[l] = (const float*)d_in[12 + 2 * l]; }

    float* out     = (float*)d_out;
    float* gendata = out;                              // [C*BB, 512] — doubles as h1
    float* label   = out + (size_t)CCLS * BB * 512;

    float* ws   = (float*)d_ws;
    float* h2   = ws;                                  // C*BB*256
    float* h3   = h2 + (size_t)CCLS * BB * 256;        // C*BB*128
    float* h4   = h2;                                  // alias: h2 dead after gemm3
    float* psum = h3 + (size_t)CCLS * BB * 128;        // C*512*NBT
    float* psq  = psum + (size_t)CCLS * 512 * NBT;
    float* scl  = psq  + (size_t)CCLS * 512 * NBT;     // C*512
    float* shf  = scl  + (size_t)CCLS * 512;

    const dim3 blk(256);

    // L1: x[K=100] -> h1(=gendata)[512], stats
    gemm_mfma_kernel<false, true><<<dim3(NBT, 4, CCLS), blk, 0, stream>>>(
        x, W[0], bs[0], nullptr, nullptr, gendata, psum, psq, 100, 512);
    combine_kernel<<<dim3(CCLS * 512 / 256), blk, 0, stream>>>(psum, psq, g[0], be[0], scl, shf, CCLS * 512);

    // L2: bn(h1)->relu -> h2[256], stats
    gemm_mfma_kernel<true, true><<<dim3(NBT, 2, CCLS), blk, 0, stream>>>(
        gendata, W[1], bs[1], scl, shf, h2, psum, psq, 512, 256);
    combine_kernel<<<dim3(CCLS * 256 / 256), blk, 0, stream>>>(psum, psq, g[1], be[1], scl, shf, CCLS * 256);

    // L3: -> h3[128], stats
    gemm_mfma_kernel<true, true><<<dim3(NBT, 1, CCLS), blk, 0, stream>>>(
        h2, W[2], bs[2], scl, shf, h3, psum, psq, 256, 128);
    combine_kernel<<<dim3(CCLS * 128 / 256), blk, 0, stream>>>(psum, psq, g[2], be[2], scl, shf, CCLS * 128);

    // L4: -> h4[256] (aliases h2; h2 dead after gemm3), stats
    gemm_mfma_kernel<true, true><<<dim3(NBT, 2, CCLS), blk, 0, stream>>>(
        h3, W[3], bs[3], scl, shf, h4, psum, psq, 128, 256);
    combine_kernel<<<dim3(CCLS * 256 / 256), blk, 0, stream>>>(psum, psq, g[3], be[3], scl, shf, CCLS * 256);

    // L5: bn(h4)->relu -> gendata[512] (no stats)
    gemm_mfma_kernel<true, false><<<dim3(NBT, 4, CCLS), blk, 0, stream>>>(
        h4, W[4], bs[4], scl, shf, gendata, nullptr, nullptr, 256, 512);

    label_kernel<<<dim3(CCLS * BB / 256), blk, 0, stream>>>(label);
}

// Round 3
// 171.431 us; speedup vs baseline: 2.6967x; 1.4601x over previous
//
#include <hip/hip_runtime.h>
#include <math.h>

#define CCLS 16
#define BB   2048
#define NBT  16   // BB / 128 b-tiles

using bf16x8 = __attribute__((ext_vector_type(8))) short;
using short8 = __attribute__((ext_vector_type(8))) short;
using f32x4  = __attribute__((ext_vector_type(4))) float;

__device__ __forceinline__ short f2bf(float f) {   // round-to-nearest-even bf16
    unsigned u = __builtin_bit_cast(unsigned, f);
    u = u + 0x7fffu + ((u >> 16) & 1u);
    return (short)(u >> 16);
}
__device__ __forceinline__ float bf2f(short s) {
    unsigned u = ((unsigned)(unsigned short)s) << 16;
    return __builtin_bit_cast(float, u);
}

// global -> LDS direct copy, 16B per lane; lds dest is wave-uniform base (+lane*16 in HW)
__device__ __forceinline__ void gll16(const void* g, void* l) {
    __builtin_amdgcn_global_load_lds(
        (const __attribute__((address_space(1))) unsigned*)g,
        (__attribute__((address_space(3))) unsigned*)l, 16, 0, 0);
}

// Fragment-major tile layout for a 128-row x 32-k bf16 tile (8 KB):
//   L(row,kb) = (row>>4)<<10 | (kb>>4)<<8 | (row&15)<<4 | (kb&15)   (kb = k byte 0..63)
// Frag read: 16 lanes read rows r..r+15 at one 16B k-chunk -> 256B contiguous: conflict-free.
// Pack tiles are stored in exactly this order -> linear global_load_lds reproduces it.

// ---------------------------------------------------------------------------
// One-time pack kernel: x and W1..W5 -> [hi 8KB][lo 8KB] tiles, fragment-major.
// Tile grid order per source: (c, row-tile, k-step) -> dst = base + bid*16384.
// ---------------------------------------------------------------------------
struct PackDesc {
    const float* src[6];
    int nrt[6];     // 128-row tiles per class
    int ksn[6];     // 32-k steps (padded)
    int kreal[6];   // real K (source row stride, pad with zeros beyond)
    int beg[7];     // tile-range starts
};

__global__ __launch_bounds__(256)
void pack_kernel(PackDesc d, char* __restrict__ base)
{
    const int bid = blockIdx.x;
    int s = 0;
    #pragma unroll
    for (int i = 0; i < 5; ++i) s += (bid >= d.beg[i + 1]);
    const int t     = bid - d.beg[s];
    const int KSn   = d.ksn[s], NRT = d.nrt[s], Kreal = d.kreal[s];
    const int ks    = t % KSn;
    const int rt    = (t / KSn) % NRT;
    const int c     = t / (KSn * NRT);
    const float* src = d.src[s] + (size_t)(c * NRT + rt) * 128 * Kreal;
    char* dst = base + (size_t)bid * 16384;
    const int tid = threadIdx.x;

    #pragma unroll
    for (int it = 0; it < 2; ++it) {
        const int row = (tid >> 2) + it * 64;
        const int cc  = tid & 3;                      // 8-elem k chunk within step
        const int q   = ((row >> 4) << 10) | (cc << 8) | ((row & 15) << 4);
        const int k0  = ks * 32 + cc * 8;
        const float* sp = src + (size_t)row * Kreal + k0;
        short hv[8], lv[8];
        #pragma unroll
        for (int j = 0; j < 8; ++j) {
            const float v = (k0 + j < Kreal) ? sp[j] : 0.f;
            hv[j] = f2bf(v);
            lv[j] = f2bf(v - bf2f(hv[j]));
        }
        *(short8*)(dst + q)        = (short8){hv[0],hv[1],hv[2],hv[3],hv[4],hv[5],hv[6],hv[7]};
        *(short8*)(dst + 8192 + q) = (short8){lv[0],lv[1],lv[2],lv[3],lv[4],lv[5],lv[6],lv[7]};
    }
}

// convert 16 fp32 (BN+ReLU applied) to hi/lo bf16 and store to LDS buffer
__device__ __forceinline__ void cvt_store(char* dstbase, int awr,
                                          const float4* a, const float4* s, const float4* t)
{
    short h[16], l[16];
    #pragma unroll
    for (int i = 0; i < 4; ++i) {
        const float e0 = fmaxf(0.f, fmaf(a[i].x, s[i].x, t[i].x));
        const float e1 = fmaxf(0.f, fmaf(a[i].y, s[i].y, t[i].y));
        const float e2 = fmaxf(0.f, fmaf(a[i].z, s[i].z, t[i].z));
        const float e3 = fmaxf(0.f, fmaf(a[i].w, s[i].w, t[i].w));
        h[i*4+0] = f2bf(e0); l[i*4+0] = f2bf(e0 - bf2f(h[i*4+0]));
        h[i*4+1] = f2bf(e1); l[i*4+1] = f2bf(e1 - bf2f(h[i*4+1]));
        h[i*4+2] = f2bf(e2); l[i*4+2] = f2bf(e2 - bf2f(h[i*4+2]));
        h[i*4+3] = f2bf(e3); l[i*4+3] = f2bf(e3 - bf2f(h[i*4+3]));
    }
    *(short8*)(dstbase + awr)              = (short8){h[0],h[1],h[2],h[3],h[4],h[5],h[6],h[7]};
    *(short8*)(dstbase + awr + 256)        = (short8){h[8],h[9],h[10],h[11],h[12],h[13],h[14],h[15]};
    *(short8*)(dstbase + 8192 + awr)       = (short8){l[0],l[1],l[2],l[3],l[4],l[5],l[6],l[7]};
    *(short8*)(dstbase + 8192 + awr + 256) = (short8){l[8],l[9],l[10],l[11],l[12],l[13],l[14],l[15]};
}

// ---------------------------------------------------------------------------
// MFMA GEMM, double-buffered LDS, single barrier per K-step.
//   Out[c,b,o] = sum_k A'[c,b,k] * W[c,o,k] + bias[c,o]
//   PREPACK_A: A' tiles prepacked (L1: x, no BN) staged via global_load_lds.
//   else:      A' = relu(A*scale+shift), reg-staged + converted (loads issued
//              before MFMA, convert+ds_write after — T14 async split).
// Tile 128x128x32; 4 waves 2x2, each 64x64 via 4x4 mfma_16x16x32_bf16 (3-product
// hi/lo fp32 emulation). LDS/buffer: AHI|ALO|WHI|WLO = 32KB, x2 buffers.
// ---------------------------------------------------------------------------
template<bool PREPACK_A, bool WRITE_STATS>
__global__ __launch_bounds__(256, 2)
void gemm2_kernel(const float* __restrict__ A, const char* __restrict__ Apk,
                  const char* __restrict__ Wpk, const float* __restrict__ bias,
                  const float* __restrict__ scale, const float* __restrict__ shift,
                  float* __restrict__ Out, float* __restrict__ psum, float* __restrict__ psq,
                  const int K, const int Fout, const int KSn)
{
    __shared__ __align__(16) char sm[65536];

    const int tid  = threadIdx.x;
    const int lane = tid & 63, wv = tid >> 6;
    const int btile = blockIdx.x, otile = blockIdx.y, c = blockIdx.z;
    const int b0 = btile * 128, o0 = otile * 128;
    const int OT = Fout >> 7;

    const char* wbase = Wpk + (size_t)((c * OT + otile) * KSn) * 16384;
    const char* abase = PREPACK_A ? (Apk + (size_t)((c * 16 + btile) * KSn) * 16384) : nullptr;

    // A reg-stage map: thread -> (row, k-half of 16)
    const int arow = tid >> 1, kh = tid & 1;
    const float* Arow = PREPACK_A ? nullptr : (A + ((size_t)c * BB + b0 + arow) * K);
    const float* scb  = PREPACK_A ? nullptr : (scale + (size_t)c * K);
    const float* shb  = PREPACK_A ? nullptr : (shift + (size_t)c * K);
    const int awr = ((arow >> 4) << 10) | ((kh << 1) << 8) | ((arow & 15) << 4);

    // frag map
    const int fr = lane & 15, fkc = lane >> 4;
    const int wrow = (wv >> 1) << 6, wcol = (wv & 1) << 6;
    const int chunk = wv << 2;

    f32x4 acc[4][4];
    #pragma unroll
    for (int mi = 0; mi < 4; ++mi)
        #pragma unroll
        for (int ni = 0; ni < 4; ++ni)
            acc[mi][ni] = (f32x4){0.f, 0.f, 0.f, 0.f};

    // ---- prologue: stage ks=0 into buffer 0 ----
    {
        #pragma unroll
        for (int i = 0; i < 4; ++i)
            gll16(wbase + ((chunk + i) << 10) + (lane << 4), sm + 16384 + ((chunk + i) << 10));
        if (PREPACK_A) {
            #pragma unroll
            for (int i = 0; i < 4; ++i)
                gll16(abase + ((chunk + i) << 10) + (lane << 4), sm + ((chunk + i) << 10));
        } else {
            const int gk = kh << 4;
            float4 a[4], s[4], t[4];
            #pragma unroll
            for (int i = 0; i < 4; ++i) {
                a[i] = *(const float4*)(Arow + gk + (i << 2));
                s[i] = *(const float4*)(scb + gk + (i << 2));
                t[i] = *(const float4*)(shb + gk + (i << 2));
            }
            cvt_store(sm, awr, a, s, t);
        }
    }
    __syncthreads();

    for (int ks = 0; ks < KSn; ++ks) {
        const int cb = (ks & 1) << 15;
        const int nb = cb ^ 32768;
        const bool hn = (ks + 1) < KSn;

        // ---- issue next-step staging (to nb) before compute ----
        float4 av[4], sv[4], tv[4];
        if (hn) {
            const size_t toff = (size_t)(ks + 1) * 16384;
            if (PREPACK_A) {
                #pragma unroll
                for (int i = 0; i < 4; ++i)
                    gll16(abase + toff + ((chunk + i) << 10) + (lane << 4),
                          sm + nb + ((chunk + i) << 10));
            } else {
                const int gk = ((ks + 1) << 5) + (kh << 4);
                #pragma unroll
                for (int i = 0; i < 4; ++i) av[i] = *(const float4*)(Arow + gk + (i << 2));
                #pragma unroll
                for (int i = 0; i < 4; ++i) {
                    sv[i] = *(const float4*)(scb + gk + (i << 2));
                    tv[i] = *(const float4*)(shb + gk + (i << 2));
                }
            }
            #pragma unroll
            for (int i = 0; i < 4; ++i)
                gll16(wbase + toff + ((chunk + i) << 10) + (lane << 4),
                      sm + nb + 16384 + ((chunk + i) << 10));
        }

        // ---- compute current (cb) ----
        // A and B use the SAME (lane-group, elem)->k map: result invariant to
        // the HW's internal k permutation (operand symmetry).
        bf16x8 ah[4], al[4], wh[4], wl[4];
        #pragma unroll
        for (int i = 0; i < 4; ++i) {
            const int ao = (((wrow >> 4) + i) << 10) | (fkc << 8) | (fr << 4);
            ah[i] = *(const bf16x8*)(sm + cb + ao);
            al[i] = *(const bf16x8*)(sm + cb + 8192 + ao);
            const int wo = (((wcol >> 4) + i) << 10) | (fkc << 8) | (fr << 4);
            wh[i] = *(const bf16x8*)(sm + cb + 16384 + wo);
            wl[i] = *(const bf16x8*)(sm + cb + 24576 + wo);
        }
        #pragma unroll
        for (int mi = 0; mi < 4; ++mi)
            #pragma unroll
            for (int ni = 0; ni < 4; ++ni) {
                acc[mi][ni] = __builtin_amdgcn_mfma_f32_16x16x32_bf16(ah[mi], wh[ni], acc[mi][ni], 0, 0, 0);
                acc[mi][ni] = __builtin_amdgcn_mfma_f32_16x16x32_bf16(ah[mi], wl[ni], acc[mi][ni], 0, 0, 0);
                acc[mi][ni] = __builtin_amdgcn_mfma_f32_16x16x32_bf16(al[mi], wh[ni], acc[mi][ni], 0, 0, 0);
            }

        // ---- finish staging next: convert + LDS write (after MFMA) ----
        if (hn && !PREPACK_A)
            cvt_store(sm + nb, awr, av, sv, tv);

        __syncthreads();   // drains vmcnt (gload_lds) + lgkmcnt (ds_write)
    }

    // ---- epilogue: bias, store, BN partial stats ----
    // C/D layout: col = lane&15, row = (lane>>4)*4 + reg
    float bv[4];
    #pragma unroll
    for (int ni = 0; ni < 4; ++ni)
        bv[ni] = bias[(size_t)c * Fout + o0 + wcol + (ni << 4) + fr];

    float p[4] = {}, q[4] = {};
    const int rsub = (lane >> 4) << 2;
    #pragma unroll
    for (int mi = 0; mi < 4; ++mi) {
        #pragma unroll
        for (int j = 0; j < 4; ++j) {
            const int row = b0 + wrow + (mi << 4) + rsub + j;
            float* op = Out + ((size_t)c * BB + row) * Fout + o0 + wcol;
            #pragma unroll
            for (int ni = 0; ni < 4; ++ni) {
                const float v = acc[mi][ni][j] + bv[ni];
                op[(ni << 4) + fr] = v;
                if (WRITE_STATS) { p[ni] += v; q[ni] += v * v; }
            }
        }
    }

    if (WRITE_STATS) {
        #pragma unroll
        for (int ni = 0; ni < 4; ++ni) {   // fold 4 row-groups per column
            p[ni] += __shfl_xor(p[ni], 16); p[ni] += __shfl_xor(p[ni], 32);
            q[ni] += __shfl_xor(q[ni], 16); q[ni] += __shfl_xor(q[ni], 32);
        }
        __syncthreads();                   // LDS frag reads done — reuse as scratch
        float* redp = (float*)sm;          // [2][128]
        float* redq = (float*)(sm + 1024);
        if (lane < 16) {
            const int base = (wv >> 1) * 128 + wcol;
            #pragma unroll
            for (int ni = 0; ni < 4; ++ni) {
                redp[base + (ni << 4) + fr] = p[ni];
                redq[base + (ni << 4) + fr] = q[ni];
            }
        }
        __syncthreads();
        if (tid < 128) {
            const float sp = redp[tid] + redp[128 + tid];
            const float sq = redq[tid] + redq[128 + tid];
            const size_t o = ((size_t)c * Fout + o0 + tid) * NBT + btile;
            psum[o] = sp;
            psq[o]  = sq;
        }
    }
}

// Fold NBT partials -> BN scale/shift per (c, feature). Deterministic order.
__global__ __launch_bounds__(256)
void combine_kernel(const float* __restrict__ psum, const float* __restrict__ psq,
                    const float* __restrict__ g, const float* __restrict__ be,
                    float* __restrict__ scale, float* __restrict__ shift, int n)
{
    const int idx = blockIdx.x * 256 + threadIdx.x;
    if (idx >= n) return;
    float s = 0.f, q = 0.f;
    #pragma unroll
    for (int t = 0; t < NBT; ++t) { s += psum[idx * NBT + t]; q += psq[idx * NBT + t]; }
    const float mean = s * (1.f / BB);
    const float var  = q * (1.f / BB) - mean * mean;
    const float rstd = rsqrtf(var + 1e-5f);
    const float scv  = g[idx] * rstd;
    scale[idx] = scv;
    shift[idx] = fmaf(-mean, scv, be[idx]);
}

__global__ __launch_bounds__(256)
void label_kernel(float* __restrict__ out)
{
    const int i = blockIdx.x * 256 + threadIdx.x;
    out[i] = (float)(i >> 11);   // i / 2048
}

// ---------------------------------------------------------------------------
extern "C" void kernel_launch(void* const* d_in, const int* in_sizes, int n_in,
                              void* d_out, int out_size, void* d_ws, size_t ws_size,
                              hipStream_t stream)
{
    const float* x = (const float*)d_in[0];
    const float* W[5];  const float* bs[5];
    for (int l = 0; l < 5; ++l) { W[l] = (const float*)d_in[1 + 2 * l]; bs[l] = (const float*)d_in[2 + 2 * l]; }
    const float* g[4];  const float* be[4];
    for (int l = 0; l < 4; ++l) { g[l] = (const float*)d_in[11 + 2 * l]; be[l] = (const float*)d_in[12 + 2 * l]; }

    float* out     = (float*)d_out;
    float* gendata = out;                              // [C*BB, 512] — doubles as h1
    float* label   = out + (size_t)CCLS * BB * 512;

    float* ws   = (float*)d_ws;
    float* h2   = ws;                                  // C*BB*256
    float* h3   = h2 + (size_t)CCLS * BB * 256;        // C*BB*128
    float* h4   = h2;                                  // alias: h2 dead after gemm3
    float* psum = h3 + (size_t)CCLS * BB * 128;        // C*512*NBT
    float* psq  = psum + (size_t)CCLS * 512 * NBT;
    float* scl  = psq  + (size_t)CCLS * 512 * NBT;     // C*512
    float* shf  = scl  + (size_t)CCLS * 512;
    char*  pack = (char*)(shf + (size_t)CCLS * 512);   // 2560 tiles x 16KB = 41.9MB

    const char* xpk  = pack;
    const char* wpk1 = pack + (size_t)1024 * 16384;
    const char* wpk2 = pack + (size_t)1280 * 16384;
    const char* wpk3 = pack + (size_t)1792 * 16384;
    const char* wpk4 = pack + (size_t)1920 * 16384;
    const char* wpk5 = pack + (size_t)2048 * 16384;

    const dim3 blk(256);

    // one-time pack: x, W1..W5 -> fragment-major hi/lo bf16 tiles
    PackDesc pd;
    pd.src[0] = x;    pd.src[1] = W[0]; pd.src[2] = W[1];
    pd.src[3] = W[2]; pd.src[4] = W[3]; pd.src[5] = W[4];
    const int nrt[6]   = {16, 4, 2, 1, 2, 4};
    const int ksn[6]   = {4, 4, 16, 8, 4, 8};
    const int kreal[6] = {100, 100, 512, 256, 128, 256};
    const int beg[7]   = {0, 1024, 1280, 1792, 1920, 2048, 2560};
    for (int i = 0; i < 6; ++i) { pd.nrt[i] = nrt[i]; pd.ksn[i] = ksn[i]; pd.kreal[i] = kreal[i]; }
    for (int i = 0; i < 7; ++i) pd.beg[i] = beg[i];
    pack_kernel<<<dim3(2560), blk, 0, stream>>>(pd, pack);

    // L1: x[K=100->128pad] -> h1(=gendata)[512], stats   (prepacked A, no BN)
    gemm2_kernel<true, true><<<dim3(16, 4, CCLS), blk, 0, stream>>>(
        nullptr, xpk, wpk1, bs[0], nullptr, nullptr, gendata, psum, psq, 128, 512, 4);
    combine_kernel<<<dim3(CCLS * 512 / 256), blk, 0, stream>>>(psum, psq, g[0], be[0], scl, shf, CCLS * 512);

    // L2: bn(h1)->relu -> h2[256], stats
    gemm2_kernel<false, true><<<dim3(16, 2, CCLS), blk, 0, stream>>>(
        gendata, nullptr, wpk2, bs[1], scl, shf, h2, psum, psq, 512, 256, 16);
    combine_kernel<<<dim3(CCLS * 256 / 256), blk, 0, stream>>>(psum, psq, g[1], be[1], scl, shf, CCLS * 256);

    // L3: -> h3[128], stats
    gemm2_kernel<false, true><<<dim3(16, 1, CCLS), blk, 0, stream>>>(
        h2, nullptr, wpk3, bs[2], scl, shf, h3, psum, psq, 256, 128, 8);
    combine_kernel<<<dim3(CCLS * 128 / 256), blk, 0, stream>>>(psum, psq, g[2], be[2], scl, shf, CCLS * 128);

    // L4: -> h4[256] (aliases h2), stats
    gemm2_kernel<false, true><<<dim3(16, 2, CCLS), blk, 0, stream>>>(
        h3, nullptr, wpk4, bs[3], scl, shf, h4, psum, psq, 128, 256, 4);
    combine_kernel<<<dim3(CCLS * 256 / 256), blk, 0, stream>>>(psum, psq, g[3], be[3], scl, shf, CCLS * 256);

    // L5: bn(h4)->relu -> gendata[512] (no stats)
    gemm2_kernel<false, false><<<dim3(16, 4, CCLS), blk, 0, stream>>>(
        h4, nullptr, wpk5, bs[4], scl, shf, gendata, nullptr, nullptr, 256, 512, 8);

    label_kernel<<<dim3(CCLS * BB / 256), blk, 0, stream>>>(label);
}

// Round 4
// 163.216 us; speedup vs baseline: 2.8324x; 1.0503x over previous
//
#include <hip/hip_runtime.h>
#include <hip/hip_bf16.h>
#include <math.h>

#define CCLS 16
#define BB   2048
#define NBT  16   // BB / 128 b-tiles

using bf16x8 = __attribute__((ext_vector_type(8))) short;
using short8 = __attribute__((ext_vector_type(8))) short;
using f32x4  = __attribute__((ext_vector_type(4))) float;

// fp32 -> (hi, lo) bf16 split via native converts (RNE; compiler emits v_cvt_pk)
__device__ __forceinline__ void split2(float e, short& hi, short& lo) {
    __hip_bfloat16 h = __float2bfloat16(e);
    hi = __builtin_bit_cast(short, h);
    lo = __builtin_bit_cast(short, __float2bfloat16(e - __bfloat162float(h)));
}

// Fragment-major tile layout for a 128-row x 32-k bf16 tile (8 KB):
//   L(row, kchunk) = (row>>4)<<10 | kchunk<<8 | (row&15)<<4      (kchunk = k/8)
// 16 lanes of a frag-read cover 256B contiguous -> conflict-free ds/global reads.

// ---------------------------------------------------------------------------
// One-time W pack: W1..W5 -> [hi 8KB][lo 8KB] fragment-major tiles,
// tile order per source: (c, otile, ks). Zero-padded past kreal.
// ---------------------------------------------------------------------------
struct PackDesc {
    const float* src[5];
    int nrt[5];     // Fout/128
    int ksn[5];     // ceil(K/32)
    int kreal[5];
    int beg[6];
};

__global__ __launch_bounds__(256)
void pack_kernel(PackDesc d, char* __restrict__ base)
{
    const int bid = blockIdx.x;
    int s = 0;
    #pragma unroll
    for (int i = 0; i < 4; ++i) s += (bid >= d.beg[i + 1]);
    const int t    = bid - d.beg[s];
    const int ksn  = d.ksn[s], nrt = d.nrt[s], kreal = d.kreal[s];
    const int perc = nrt * ksn;
    const int c  = t / perc;
    const int r  = t - c * perc;
    const int rt = r / ksn;
    const int ks = r - rt * ksn;
    const float* src = d.src[s] + ((size_t)(c * nrt + rt) * 128) * kreal;
    char* dst = base + (size_t)bid * 16384;
    const int tid = threadIdx.x;

    #pragma unroll
    for (int it = 0; it < 2; ++it) {
        const int row = (tid >> 2) + (it << 6);
        const int cc  = tid & 3;
        const int q   = ((row >> 4) << 10) | (cc << 8) | ((row & 15) << 4);
        const int k0  = ks * 32 + cc * 8;
        const float* sp = src + (size_t)row * kreal + k0;
        float e[8];
        if (k0 + 8 <= kreal) {
            float4 v0 = *(const float4*)sp;
            float4 v1 = *(const float4*)(sp + 4);
            e[0]=v0.x; e[1]=v0.y; e[2]=v0.z; e[3]=v0.w;
            e[4]=v1.x; e[5]=v1.y; e[6]=v1.z; e[7]=v1.w;
        } else {
            #pragma unroll
            for (int j = 0; j < 8; ++j) e[j] = (k0 + j < kreal) ? sp[j] : 0.f;
        }
        short hv[8], lv[8];
        #pragma unroll
        for (int j = 0; j < 8; ++j) split2(e[j], hv[j], lv[j]);
        *(short8*)(dst + q)        = (short8){hv[0],hv[1],hv[2],hv[3],hv[4],hv[5],hv[6],hv[7]};
        *(short8*)(dst + 8192 + q) = (short8){lv[0],lv[1],lv[2],lv[3],lv[4],lv[5],lv[6],lv[7]};
    }
}

// convert 16 fp32 (optional BN+ReLU from LDS tables) -> hi/lo bf16, store to LDS
template<bool BN>
__device__ __forceinline__ void cvt_store(char* dstbase, int awr, const float4* a,
                                          const float* scs, const float* shs, int gk)
{
    float e[16];
    #pragma unroll
    for (int i = 0; i < 4; ++i) {
        e[i*4+0] = a[i].x; e[i*4+1] = a[i].y; e[i*4+2] = a[i].z; e[i*4+3] = a[i].w;
    }
    if (BN) {
        #pragma unroll
        for (int i = 0; i < 4; ++i) {
            const float4 sc = *(const float4*)(scs + gk + (i << 2));
            const float4 sh = *(const float4*)(shs + gk + (i << 2));
            e[i*4+0] = fmaxf(0.f, fmaf(e[i*4+0], sc.x, sh.x));
            e[i*4+1] = fmaxf(0.f, fmaf(e[i*4+1], sc.y, sh.y));
            e[i*4+2] = fmaxf(0.f, fmaf(e[i*4+2], sc.z, sh.z));
            e[i*4+3] = fmaxf(0.f, fmaf(e[i*4+3], sc.w, sh.w));
        }
    }
    short h[16], l[16];
    #pragma unroll
    for (int j = 0; j < 16; ++j) split2(e[j], h[j], l[j]);
    *(short8*)(dstbase + awr)              = (short8){h[0],h[1],h[2],h[3],h[4],h[5],h[6],h[7]};
    *(short8*)(dstbase + awr + 256)        = (short8){h[8],h[9],h[10],h[11],h[12],h[13],h[14],h[15]};
    *(short8*)(dstbase + 8192 + awr)       = (short8){l[0],l[1],l[2],l[3],l[4],l[5],l[6],l[7]};
    *(short8*)(dstbase + 8192 + awr + 256) = (short8){l[8],l[9],l[10],l[11],l[12],l[13],l[14],l[15]};
}

// ---------------------------------------------------------------------------
// MFMA GEMM. A (fp32) reg-staged -> [BN+ReLU] -> hi/lo bf16 in LDS (dbuf,
// 1 barrier/step). W fragments loaded global->VGPR from fragment-major pack
// (no LDS). BN scale/shift computed in-prologue from previous layer's partial
// stats (folded combine). Deterministic partial stats of output per btile.
// Tile 128x128x32; 4 waves 2x2, each 64x64 = 4x4 mfma_16x16x32_bf16 x3 (hi/lo).
// ---------------------------------------------------------------------------
template<bool FUSE_BN, bool WRITE_STATS>
__global__ __launch_bounds__(256, 3)
void gemm3_kernel(const float* __restrict__ A,       // [C][BB][K] raw (pre-BN)
                  const char*  __restrict__ Wpk,     // fragment-major hi/lo tiles
                  const float* __restrict__ bias,    // [C][Fout]
                  const float* __restrict__ psumIn,  // [C][K][NBT] (FUSE_BN)
                  const float* __restrict__ psqIn,
                  const float* __restrict__ gIn,     // [C][K]
                  const float* __restrict__ beIn,
                  float* __restrict__ Out,           // [C][BB][Fout]
                  float* __restrict__ psumOut, float* __restrict__ psqOut,
                  const int K, const int Fout, const int KSn)
{
    __shared__ __align__(16) char sm[36864];          // 2x16KB A dbuf + scs/shs
    float* scs = (float*)(sm + 32768);
    float* shs = (float*)(sm + 34816);

    const int tid  = threadIdx.x;
    const int lane = tid & 63, wv = tid >> 6;
    const int btile = blockIdx.x, otile = blockIdx.y, c = blockIdx.z;
    const int b0 = btile * 128, o0 = otile * 128;
    const int OT = Fout >> 7;

    const char* wbase = Wpk + (size_t)((c * OT + otile) * KSn) * 16384;

    // ---- folded combine: BN scale/shift for this layer's INPUT features ----
    if (FUSE_BN) {
        for (int f = tid; f < K; f += 256) {
            const float* ps = psumIn + ((size_t)c * K + f) * NBT;
            const float* pq = psqIn  + ((size_t)c * K + f) * NBT;
            float s = 0.f, q = 0.f;
            #pragma unroll
            for (int t = 0; t < NBT; t += 4) {
                float4 a4 = *(const float4*)(ps + t);
                float4 b4 = *(const float4*)(pq + t);
                s += (a4.x + a4.y) + (a4.z + a4.w);
                q += (b4.x + b4.y) + (b4.z + b4.w);
            }
            const float mean = s * (1.f / BB);
            const float var  = q * (1.f / BB) - mean * mean;
            const float rstd = rsqrtf(var + 1e-5f);
            const float scv  = gIn[(size_t)c * K + f] * rstd;
            scs[f] = scv;
            shs[f] = fmaf(-mean, scv, beIn[(size_t)c * K + f]);
        }
    }

    // A staging map: thread -> (row, k-half of 16)
    const int arow = tid >> 1, kh = tid & 1;
    const float* Arow = A + ((size_t)c * BB + b0 + arow) * K;
    const int awr = ((arow >> 4) << 10) | ((kh << 1) << 8) | ((arow & 15) << 4);

    // fragment map
    const int fr = lane & 15, fkc = lane >> 4;
    const int wrow = (wv >> 1) << 6, wcol = (wv & 1) << 6;

    f32x4 acc[4][4];
    #pragma unroll
    for (int mi = 0; mi < 4; ++mi)
        #pragma unroll
        for (int ni = 0; ni < 4; ++ni)
            acc[mi][ni] = (f32x4){0.f, 0.f, 0.f, 0.f};

    if (FUSE_BN) __syncthreads();   // scs/shs ready before first cvt

    // ---- prologue: stage ks=0 into buf0 ----
    {
        float4 av[4];
        const int gkb = kh << 4;
        #pragma unroll
        for (int i = 0; i < 4; ++i) {
            const int gk = gkb + (i << 2);
            if (gk + 4 <= K) av[i] = *(const float4*)(Arow + gk);
            else {
                float e0 = (gk+0 < K) ? Arow[gk+0] : 0.f;
                float e1 = (gk+1 < K) ? Arow[gk+1] : 0.f;
                float e2 = (gk+2 < K) ? Arow[gk+2] : 0.f;
                float e3 = (gk+3 < K) ? Arow[gk+3] : 0.f;
                av[i] = make_float4(e0, e1, e2, e3);
            }
        }
        cvt_store<FUSE_BN>(sm, awr, av, scs, shs, gkb);
    }
    __syncthreads();

    for (int ks = 0; ks < KSn; ++ks) {
        const int cb = (ks & 1) << 14;
        const int nb = cb ^ 16384;
        const bool hn = (ks + 1) < KSn;

        // issue next-step A loads early (T14 issue-early / write-late)
        float4 av[4];
        int gkb = 0;
        if (hn) {
            gkb = ((ks + 1) << 5) + (kh << 4);
            #pragma unroll
            for (int i = 0; i < 4; ++i) {
                const int gk = gkb + (i << 2);
                if (gk + 4 <= K) av[i] = *(const float4*)(Arow + gk);
                else {
                    float e0 = (gk+0 < K) ? Arow[gk+0] : 0.f;
                    float e1 = (gk+1 < K) ? Arow[gk+1] : 0.f;
                    float e2 = (gk+2 < K) ? Arow[gk+2] : 0.f;
                    float e3 = (gk+3 < K) ? Arow[gk+3] : 0.f;
                    av[i] = make_float4(e0, e1, e2, e3);
                }
            }
        }

        // W fragments: global -> VGPR (coalesced 1KB/wave per frag pair)
        const char* wt = wbase + (size_t)ks * 16384;
        bf16x8 wh[4], wl[4];
        #pragma unroll
        for (int i = 0; i < 4; ++i) {
            const int wo = (((wcol >> 4) + i) << 10) | (fkc << 8) | (fr << 4);
            wh[i] = *(const bf16x8*)(wt + wo);
            wl[i] = *(const bf16x8*)(wt + 8192 + wo);
        }
        // A fragments: LDS -> VGPR
        bf16x8 ah[4], al[4];
        #pragma unroll
        for (int i = 0; i < 4; ++i) {
            const int ao = (((wrow >> 4) + i) << 10) | (fkc << 8) | (fr << 4);
            ah[i] = *(const bf16x8*)(sm + cb + ao);
            al[i] = *(const bf16x8*)(sm + cb + 8192 + ao);
        }
        // 48 MFMA (hi*hi + hi*lo + lo*hi; A/B share k-map -> k-perm invariant)
        #pragma unroll
        for (int mi = 0; mi < 4; ++mi)
            #pragma unroll
            for (int ni = 0; ni < 4; ++ni) {
                acc[mi][ni] = __builtin_amdgcn_mfma_f32_16x16x32_bf16(ah[mi], wh[ni], acc[mi][ni], 0, 0, 0);
                acc[mi][ni] = __builtin_amdgcn_mfma_f32_16x16x32_bf16(ah[mi], wl[ni], acc[mi][ni], 0, 0, 0);
                acc[mi][ni] = __builtin_amdgcn_mfma_f32_16x16x32_bf16(al[mi], wh[ni], acc[mi][ni], 0, 0, 0);
            }

        // write-late: convert + LDS store for next step
        if (hn) cvt_store<FUSE_BN>(sm + nb, awr, av, scs, shs, gkb);

        __syncthreads();
    }

    // ---- epilogue: bias, store, deterministic partial BN stats ----
    // C/D layout: col = lane&15, row = (lane>>4)*4 + reg
    float bv[4];
    #pragma unroll
    for (int ni = 0; ni < 4; ++ni)
        bv[ni] = bias[(size_t)c * Fout + o0 + wcol + (ni << 4) + fr];

    float p[4] = {}, q[4] = {};
    const int rsub = (lane >> 4) << 2;
    #pragma unroll
    for (int mi = 0; mi < 4; ++mi) {
        #pragma unroll
        for (int j = 0; j < 4; ++j) {
            const int row = b0 + wrow + (mi << 4) + rsub + j;
            float* op = Out + ((size_t)c * BB + row) * Fout + o0 + wcol;
            #pragma unroll
            for (int ni = 0; ni < 4; ++ni) {
                const float v = acc[mi][ni][j] + bv[ni];
                op[(ni << 4) + fr] = v;
                if (WRITE_STATS) { p[ni] += v; q[ni] += v * v; }
            }
        }
    }

    if (WRITE_STATS) {
        #pragma unroll
        for (int ni = 0; ni < 4; ++ni) {   // fold 4 row-groups per column
            p[ni] += __shfl_xor(p[ni], 16); p[ni] += __shfl_xor(p[ni], 32);
            q[ni] += __shfl_xor(q[ni], 16); q[ni] += __shfl_xor(q[ni], 32);
        }
        __syncthreads();                   // LDS frag reads done — reuse as scratch
        float* redp = (float*)sm;          // [2][128]
        float* redq = (float*)(sm + 1024);
        if (lane < 16) {
            const int base = (wv >> 1) * 128 + wcol;
            #pragma unroll
            for (int ni = 0; ni < 4; ++ni) {
                redp[base + (ni << 4) + fr] = p[ni];
                redq[base + (ni << 4) + fr] = q[ni];
            }
        }
        __syncthreads();
        if (tid < 128) {
            const float sp = redp[tid] + redp[128 + tid];
            const float sq = redq[tid] + redq[128 + tid];
            const size_t o = ((size_t)c * Fout + o0 + tid) * NBT + btile;
            psumOut[o] = sp;
            psqOut[o]  = sq;
        }
    }
}

__global__ __launch_bounds__(256)
void label_kernel(float* __restrict__ out)
{
    const int i = blockIdx.x * 256 + threadIdx.x;
    out[i] = (float)(i >> 11);   // i / 2048
}

// ---------------------------------------------------------------------------
extern "C" void kernel_launch(void* const* d_in, const int* in_sizes, int n_in,
                              void* d_out, int out_size, void* d_ws, size_t ws_size,
                              hipStream_t stream)
{
    const float* x = (const float*)d_in[0];
    const float* W[5];  const float* bs[5];
    for (int l = 0; l < 5; ++l) { W[l] = (const float*)d_in[1 + 2 * l]; bs[l] = (const float*)d_in[2 + 2 * l]; }
    const float* g[4];  const float* be[4];
    for (int l = 0; l < 4; ++l) { g[l] = (const float*)d_in[11 + 2 * l]; be[l] = (const float*)d_in[12 + 2 * l]; }

    float* out     = (float*)d_out;
    float* gendata = out;                              // [C*BB, 512] — doubles as h1
    float* label   = out + (size_t)CCLS * BB * 512;

    float* ws  = (float*)d_ws;
    float* h2  = ws;                                   // C*BB*256 (32MB)
    float* h3  = h2 + (size_t)CCLS * BB * 256;         // C*BB*128 (16MB)
    float* h4  = h2;                                   // alias: h2 dead after G3
    float* ps1 = h3 + (size_t)CCLS * BB * 128;         // per-layer stats, 131072 ea
    float* pq1 = ps1 + 131072;
    float* ps2 = pq1 + 131072;
    float* pq2 = ps2 + 131072;
    float* ps3 = pq2 + 131072;
    float* pq3 = ps3 + 131072;
    float* ps4 = pq3 + 131072;
    float* pq4 = ps4 + 131072;
    char*  pack = (char*)(pq4 + 131072);               // 1536 x 16KB = 24MB

    const char* wpk1 = pack;
    const char* wpk2 = pack + (size_t)256  * 16384;
    const char* wpk3 = pack + (size_t)768  * 16384;
    const char* wpk4 = pack + (size_t)896  * 16384;
    const char* wpk5 = pack + (size_t)1024 * 16384;

    const dim3 blk(256);

    // one-time W pack -> fragment-major hi/lo bf16 tiles
    PackDesc pd;
    pd.src[0] = W[0]; pd.src[1] = W[1]; pd.src[2] = W[2]; pd.src[3] = W[3]; pd.src[4] = W[4];
    const int nrt[5]   = {4, 2, 1, 2, 4};
    const int ksn[5]   = {4, 16, 8, 4, 8};
    const int kreal[5] = {100, 512, 256, 128, 256};
    const int beg[6]   = {0, 256, 768, 896, 1024, 1536};
    for (int i = 0; i < 5; ++i) { pd.nrt[i] = nrt[i]; pd.ksn[i] = ksn[i]; pd.kreal[i] = kreal[i]; }
    for (int i = 0; i < 6; ++i) pd.beg[i] = beg[i];
    pack_kernel<<<dim3(1536), blk, 0, stream>>>(pd, pack);

    // G1: x[K=100] -> h1(=gendata)[512], stats -> ps1
    gemm3_kernel<false, true><<<dim3(16, 4, CCLS), blk, 0, stream>>>(
        x, wpk1, bs[0], nullptr, nullptr, nullptr, nullptr,
        gendata, ps1, pq1, 100, 512, 4);

    // G2: bn1(h1)->relu -> h2[256], stats -> ps2
    gemm3_kernel<true, true><<<dim3(16, 2, CCLS), blk, 0, stream>>>(
        gendata, wpk2, bs[1], ps1, pq1, g[0], be[0],
        h2, ps2, pq2, 512, 256, 16);

    // G3: bn2(h2)->relu -> h3[128], stats -> ps3
    gemm3_kernel<true, true><<<dim3(16, 1, CCLS), blk, 0, stream>>>(
        h2, wpk3, bs[2], ps2, pq2, g[1], be[1],
        h3, ps3, pq3, 256, 128, 8);

    // G4: bn3(h3)->relu -> h4[256] (aliases h2), stats -> ps4
    gemm3_kernel<true, true><<<dim3(16, 2, CCLS), blk, 0, stream>>>(
        h3, wpk4, bs[3], ps3, pq3, g[2], be[2],
        h4, ps4, pq4, 128, 256, 4);

    // G5: bn4(h4)->relu -> gendata[512] (no stats)
    gemm3_kernel<true, false><<<dim3(16, 4, CCLS), blk, 0, stream>>>(
        h4, wpk5, bs[4], ps4, pq4, g[3], be[3],
        gendata, nullptr, nullptr, 256, 512, 8);

    label_kernel<<<dim3(CCLS * BB / 256), blk, 0, stream>>>(label);
}

// Round 5
// 154.871 us; speedup vs baseline: 2.9850x; 1.0539x over previous
//
#include <hip/hip_runtime.h>
#include <hip/hip_bf16.h>
#include <math.h>

#define CCLS 16
#define BB   2048

using bf16x8 = __attribute__((ext_vector_type(8))) short;
using short8 = __attribute__((ext_vector_type(8))) short;
using f32x4  = __attribute__((ext_vector_type(4))) float;

// fp32 -> (hi, lo) bf16 split (RNE; hi+lo reproduces ~24 mantissa bits)
__device__ __forceinline__ void split2(float e, short& hi, short& lo) {
    __hip_bfloat16 h = __float2bfloat16(e);
    hi = __builtin_bit_cast(short, h);
    lo = __builtin_bit_cast(short, __float2bfloat16(e - __bfloat162float(h)));
}

// LDS-visibility barrier that does NOT drain vmcnt: global loads stay in
// flight across it (the compiler inserts counted vmcnt(N) before uses).
__device__ __forceinline__ void soft_barrier() {
    asm volatile("s_waitcnt lgkmcnt(0)" ::: "memory");
    __builtin_amdgcn_s_barrier();
    asm volatile("" ::: "memory");
}

// Fragment-major tile layout for a BM-row x 32-k bf16 tile:
//   L(row, kchunk) = (row>>4)<<10 | kchunk<<8 | (row&15)<<4   (kchunk = k/8)
// A 16-lane frag read covers 256B contiguous -> conflict-free.

// ---------------------------------------------------------------------------
// One-time W pack: W1..W5 -> [hi 8KB][lo 8KB] fragment-major 128x32 tiles,
// tile order per source: (c, otile, ks). Zero-padded past kreal.
// ---------------------------------------------------------------------------
struct PackDesc {
    const float* src[5];
    int nrt[5];     // Fout/128
    int ksn[5];     // ceil(K/32)
    int kreal[5];
    int beg[6];
};

__global__ __launch_bounds__(256)
void pack_kernel(PackDesc d, char* __restrict__ base)
{
    const int bid = blockIdx.x;
    int s = 0;
    #pragma unroll
    for (int i = 0; i < 4; ++i) s += (bid >= d.beg[i + 1]);
    const int t    = bid - d.beg[s];
    const int ksn  = d.ksn[s], nrt = d.nrt[s], kreal = d.kreal[s];
    const int perc = nrt * ksn;
    const int c  = t / perc;
    const int r  = t - c * perc;
    const int rt = r / ksn;
    const int ks = r - rt * ksn;
    const float* src = d.src[s] + ((size_t)(c * nrt + rt) * 128) * kreal;
    char* dst = base + (size_t)bid * 16384;
    const int tid = threadIdx.x;

    #pragma unroll
    for (int it = 0; it < 2; ++it) {
        const int row = (tid >> 2) + (it << 6);
        const int cc  = tid & 3;
        const int q   = ((row >> 4) << 10) | (cc << 8) | ((row & 15) << 4);
        const int k0  = ks * 32 + cc * 8;
        const float* sp = src + (size_t)row * kreal + k0;
        float e[8];
        if (k0 + 8 <= kreal) {
            float4 v0 = *(const float4*)sp;
            float4 v1 = *(const float4*)(sp + 4);
            e[0]=v0.x; e[1]=v0.y; e[2]=v0.z; e[3]=v0.w;
            e[4]=v1.x; e[5]=v1.y; e[6]=v1.z; e[7]=v1.w;
        } else {
            #pragma unroll
            for (int j = 0; j < 8; ++j) e[j] = (k0 + j < kreal) ? sp[j] : 0.f;
        }
        short hv[8], lv[8];
        #pragma unroll
        for (int j = 0; j < 8; ++j) split2(e[j], hv[j], lv[j]);
        *(short8*)(dst + q)        = (short8){hv[0],hv[1],hv[2],hv[3],hv[4],hv[5],hv[6],hv[7]};
        *(short8*)(dst + 8192 + q) = (short8){lv[0],lv[1],lv[2],lv[3],lv[4],lv[5],lv[6],lv[7]};
    }
}

// ---------------------------------------------------------------------------
// MFMA GEMM, fp32 via bf16 hi/lo 3-product emulation.
//  - A (fp32) reg-staged -> [BN+ReLU] -> hi/lo bf16 in LDS (double-buffered,
//    ONE soft barrier per K-step; vmcnt never drained in-loop).
//  - W fragments global->VGPR, REGISTER double-buffered one step ahead.
//  - BN scale/shift of the INPUT computed in-prologue from producer's
//    deterministic partial stats (folded combine).
//  - Deterministic partial stats of the OUTPUT per (c, feature, btile).
// Tile BM x 128 x 32; 4 waves 2x2; per wave (BM/2)x64 = (BM/32)x4 frags.
// ---------------------------------------------------------------------------
template<int BM, int K, bool FUSE_BN, bool WRITE_STATS>
__global__ __launch_bounds__(256, 2)
void gemm4_kernel(const float* __restrict__ A, const char* __restrict__ Wpk,
                  const float* __restrict__ bias,
                  const float* __restrict__ psumIn, const float* __restrict__ psqIn,
                  const float* __restrict__ gIn, const float* __restrict__ beIn,
                  float* __restrict__ Out,
                  float* __restrict__ psumOut, float* __restrict__ psqOut,
                  const int Fout, const int nbtIn)
{
    constexpr int KS    = (K + 31) / 32;
    constexpr int PLANE = BM * 64;          // bytes per hi (or lo) plane
    constexpr int BUF   = PLANE * 2;        // hi+lo pair
    constexpr int MI    = BM / 32;          // M frags per wave
    constexpr int NV    = BM / 32;          // float4 A-loads per thread

    __shared__ __align__(16) char sm[2 * BUF + 4096];
    float* scs = (float*)(sm + 2 * BUF);
    float* shs = scs + 512;

    const int tid   = threadIdx.x;
    const int btile = blockIdx.x, otile = blockIdx.y, c = blockIdx.z;

    // ---- folded combine: BN scale/shift for this layer's INPUT features ----
    if (FUSE_BN) {
        for (int f = tid; f < K; f += 256) {
            const float* ps = psumIn + ((size_t)c * K + f) * nbtIn;
            const float* pq = psqIn  + ((size_t)c * K + f) * nbtIn;
            float s = 0.f, q = 0.f;
            for (int t = 0; t < nbtIn; t += 4) {
                float4 a4 = *(const float4*)(ps + t);
                float4 b4 = *(const float4*)(pq + t);
                s += (a4.x + a4.y) + (a4.z + a4.w);
                q += (b4.x + b4.y) + (b4.z + b4.w);
            }
            const float mean = s * (1.f / BB);
            const float var  = q * (1.f / BB) - mean * mean;
            const float rstd = rsqrtf(var + 1e-5f);
            const float scv  = gIn[(size_t)c * K + f] * rstd;
            scs[f] = scv;
            shs[f] = fmaf(-mean, scv, beIn[(size_t)c * K + f]);
        }
        __syncthreads();
    }

    const int b0 = btile * BM, o0 = otile * 128;
    const int OT = Fout >> 7;
    const char* wbase = Wpk + (size_t)((c * OT + otile) * KS) * 16384;

    // A staging map
    const int arow = (BM == 128) ? (tid >> 1) : (tid >> 2);
    const int asub = (BM == 128) ? (tid & 1)  : (tid & 3);
    const int ak0  = (BM == 128) ? (asub << 4) : (asub << 3);
    const int kch  = (BM == 128) ? (asub << 1) : asub;
    const int awr  = ((arow >> 4) << 10) | (kch << 8) | ((arow & 15) << 4);
    const float* Arow = A + ((size_t)c * BB + b0 + arow) * K;

    // fragment map
    const int lane = tid & 63, wv = tid >> 6;
    const int fr = lane & 15, fkc = lane >> 4;
    const int wrow = (BM == 128) ? ((wv >> 1) << 6) : ((wv >> 1) << 5);
    const int wcol = (wv & 1) << 6;
    const int wrg = wrow >> 4, wcg = wcol >> 4;

    auto loadA = [&](float4* av, int gk0) {
        #pragma unroll
        for (int i = 0; i < NV; ++i) {
            const int gk = gk0 + (i << 2);
            if constexpr ((K & 31) != 0) {
                if (gk + 4 <= K) av[i] = *(const float4*)(Arow + gk);
                else {
                    av[i].x = (gk + 0 < K) ? Arow[gk + 0] : 0.f;
                    av[i].y = (gk + 1 < K) ? Arow[gk + 1] : 0.f;
                    av[i].z = (gk + 2 < K) ? Arow[gk + 2] : 0.f;
                    av[i].w = (gk + 3 < K) ? Arow[gk + 3] : 0.f;
                }
            } else {
                av[i] = *(const float4*)(Arow + gk);
            }
        }
    };
    auto loadW = [&](bf16x8* w, int ks) {
        const char* wt = wbase + (size_t)ks * 16384;
        #pragma unroll
        for (int i = 0; i < 4; ++i) {
            const int wo = ((wcg + i) << 10) | (fkc << 8) | (fr << 4);
            w[i]     = *(const bf16x8*)(wt + wo);
            w[4 + i] = *(const bf16x8*)(wt + 8192 + wo);
        }
    };
    auto cvtStore = [&](char* dstbase, const float4* a, int gk0) {
        float e[NV * 4];
        #pragma unroll
        for (int i = 0; i < NV; ++i) {
            e[i*4+0] = a[i].x; e[i*4+1] = a[i].y; e[i*4+2] = a[i].z; e[i*4+3] = a[i].w;
        }
        if constexpr (FUSE_BN) {
            #pragma unroll
            for (int i = 0; i < NV; ++i) {
                const float4 sc = *(const float4*)(scs + gk0 + (i << 2));
                const float4 sh = *(const float4*)(shs + gk0 + (i << 2));
                e[i*4+0] = fmaxf(0.f, fmaf(e[i*4+0], sc.x, sh.x));
                e[i*4+1] = fmaxf(0.f, fmaf(e[i*4+1], sc.y, sh.y));
                e[i*4+2] = fmaxf(0.f, fmaf(e[i*4+2], sc.z, sh.z));
                e[i*4+3] = fmaxf(0.f, fmaf(e[i*4+3], sc.w, sh.w));
            }
        }
        short h[NV*4], l[NV*4];
        #pragma unroll
        for (int j = 0; j < NV*4; ++j) split2(e[j], h[j], l[j]);
        *(short8*)(dstbase + awr)         = (short8){h[0],h[1],h[2],h[3],h[4],h[5],h[6],h[7]};
        *(short8*)(dstbase + PLANE + awr) = (short8){l[0],l[1],l[2],l[3],l[4],l[5],l[6],l[7]};
        if constexpr (NV == 4) {
            *(short8*)(dstbase + awr + 256)         = (short8){h[8],h[9],h[10],h[11],h[12],h[13],h[14],h[15]};
            *(short8*)(dstbase + PLANE + awr + 256) = (short8){l[8],l[9],l[10],l[11],l[12],l[13],l[14],l[15]};
        }
    };

    f32x4 acc[MI][4];
    #pragma unroll
    for (int mi = 0; mi < MI; ++mi)
        #pragma unroll
        for (int ni = 0; ni < 4; ++ni)
            acc[mi][ni] = (f32x4){0.f, 0.f, 0.f, 0.f};

    bf16x8 wc[8], wn[8];

    // ---- prologue: W(0) -> regs, A(0) -> LDS buf0 ----
    {
        float4 av[NV];
        loadA(av, ak0);
        loadW(wc, 0);
        cvtStore(sm, av, ak0);
    }
    soft_barrier();

    // ---- main loop: 1 soft barrier / step; W reg-dbuf; A issue-early ----
    #pragma unroll 2
    for (int ks = 0; ks < KS; ++ks) {
        const int cb = (ks & 1) ? BUF : 0;
        const int nb = cb ^ BUF;
        const bool hn = (ks + 1) < KS;

        float4 avn[NV];
        if (hn) {
            loadA(avn, ((ks + 1) << 5) + ak0);   // global, consumed post-MFMA
            loadW(wn, ks + 1);                   // global, consumed NEXT step
        }

        bf16x8 ah[MI], al[MI];
        #pragma unroll
        for (int i = 0; i < MI; ++i) {
            const int ao = ((wrg + i) << 10) | (fkc << 8) | (fr << 4);
            ah[i] = *(const bf16x8*)(sm + cb + ao);
            al[i] = *(const bf16x8*)(sm + cb + PLANE + ao);
        }
        // 3-product emulation; A/B share the k-map -> k-perm invariant
        #pragma unroll
        for (int mi = 0; mi < MI; ++mi)
            #pragma unroll
            for (int ni = 0; ni < 4; ++ni) {
                acc[mi][ni] = __builtin_amdgcn_mfma_f32_16x16x32_bf16(ah[mi], wc[ni],     acc[mi][ni], 0, 0, 0);
                acc[mi][ni] = __builtin_amdgcn_mfma_f32_16x16x32_bf16(ah[mi], wc[4 + ni], acc[mi][ni], 0, 0, 0);
                acc[mi][ni] = __builtin_amdgcn_mfma_f32_16x16x32_bf16(al[mi], wc[ni],     acc[mi][ni], 0, 0, 0);
            }

        if (hn) cvtStore(sm + nb, avn, ((ks + 1) << 5) + ak0);   // write-late
        soft_barrier();
        if (hn) {
            #pragma unroll
            for (int i = 0; i < 8; ++i) wc[i] = wn[i];           // free via unroll-2 SSA
        }
    }

    // ---- epilogue: bias, store, deterministic partial BN stats ----
    // C/D layout: col = lane&15, row = (lane>>4)*4 + reg
    float bv[4];
    #pragma unroll
    for (int ni = 0; ni < 4; ++ni)
        bv[ni] = bias[(size_t)c * Fout + o0 + wcol + (ni << 4) + fr];

    float p[4] = {}, q[4] = {};
    const int rsub = (lane >> 4) << 2;
    #pragma unroll
    for (int mi = 0; mi < MI; ++mi) {
        #pragma unroll
        for (int j = 0; j < 4; ++j) {
            const int row = b0 + wrow + (mi << 4) + rsub + j;
            float* op = Out + ((size_t)c * BB + row) * Fout + o0 + wcol;
            #pragma unroll
            for (int ni = 0; ni < 4; ++ni) {
                const float v = acc[mi][ni][j] + bv[ni];
                op[(ni << 4) + fr] = v;
                if (WRITE_STATS) { p[ni] += v; q[ni] += v * v; }
            }
        }
    }

    if (WRITE_STATS) {
        #pragma unroll
        for (int ni = 0; ni < 4; ++ni) {
            p[ni] += __shfl_xor(p[ni], 16); p[ni] += __shfl_xor(p[ni], 32);
            q[ni] += __shfl_xor(q[ni], 16); q[ni] += __shfl_xor(q[ni], 32);
        }
        float* redp = (float*)sm;          // [2][128] scratch (loop is done)
        float* redq = (float*)(sm + 1024);
        if (lane < 16) {
            const int base = (wv >> 1) * 128 + wcol;
            #pragma unroll
            for (int ni = 0; ni < 4; ++ni) {
                redp[base + (ni << 4) + fr] = p[ni];
                redq[base + (ni << 4) + fr] = q[ni];
            }
        }
        __syncthreads();
        if (tid < 128) {
            const float sp = redp[tid] + redp[128 + tid];
            const float sq = redq[tid] + redq[128 + tid];
            const size_t o = ((size_t)c * Fout + o0 + tid) * gridDim.x + btile;
            psumOut[o] = sp;
            psqOut[o]  = sq;
        }
    }
}

__global__ __launch_bounds__(256)
void label_kernel(float* __restrict__ out)
{
    const int i = blockIdx.x * 256 + threadIdx.x;
    out[i] = (float)(i >> 11);   // i / 2048
}

// ---------------------------------------------------------------------------
extern "C" void kernel_launch(void* const* d_in, const int* in_sizes, int n_in,
                              void* d_out, int out_size, void* d_ws, size_t ws_size,
                              hipStream_t stream)
{
    const float* x = (const float*)d_in[0];
    const float* W[5];  const float* bs[5];
    for (int l = 0; l < 5; ++l) { W[l] = (const float*)d_in[1 + 2 * l]; bs[l] = (const float*)d_in[2 + 2 * l]; }
    const float* g[4];  const float* be[4];
    for (int l = 0; l < 4; ++l) { g[l] = (const float*)d_in[11 + 2 * l]; be[l] = (const float*)d_in[12 + 2 * l]; }

    float* out     = (float*)d_out;
    float* gendata = out;                              // [C*BB, 512] — doubles as h1
    float* label   = out + (size_t)CCLS * BB * 512;

    float* ws  = (float*)d_ws;
    float* h2  = ws;                                   // 8388608 f (32MB)
    float* h3  = h2 + 8388608;                         // 4194304 f (16MB)
    float* h4  = h2;                                   // alias: h2 dead after G3
    float* ps1 = h3 + 4194304;                         // 16*512*16
    float* pq1 = ps1 + 131072;
    float* ps2 = pq1 + 131072;                         // 16*256*16
    float* pq2 = ps2 + 65536;
    float* ps3 = pq2 + 65536;                          // 16*128*32
    float* pq3 = ps3 + 65536;
    float* ps4 = pq3 + 65536;                          // 16*256*16
    float* pq4 = ps4 + 65536;
    char*  pack = (char*)(pq4 + 65536);                // 1536 x 16KB = 24MB

    const char* wpk1 = pack;
    const char* wpk2 = pack + (size_t)256  * 16384;
    const char* wpk3 = pack + (size_t)768  * 16384;
    const char* wpk4 = pack + (size_t)896  * 16384;
    const char* wpk5 = pack + (size_t)1024 * 16384;

    const dim3 blk(256);

    // one-time W pack -> fragment-major hi/lo bf16 tiles
    PackDesc pd;
    pd.src[0] = W[0]; pd.src[1] = W[1]; pd.src[2] = W[2]; pd.src[3] = W[3]; pd.src[4] = W[4];
    const int nrt[5]   = {4, 2, 1, 2, 4};
    const int ksn[5]   = {4, 16, 8, 4, 8};
    const int kreal[5] = {100, 512, 256, 128, 256};
    const int beg[6]   = {0, 256, 768, 896, 1024, 1536};
    for (int i = 0; i < 5; ++i) { pd.nrt[i] = nrt[i]; pd.ksn[i] = ksn[i]; pd.kreal[i] = kreal[i]; }
    for (int i = 0; i < 6; ++i) pd.beg[i] = beg[i];
    pack_kernel<<<dim3(1536), blk, 0, stream>>>(pd, pack);

    // G1: x[K=100] -> h1(=gendata)[512], stats -> ps1 (nbtOut=16)
    gemm4_kernel<128, 100, false, true><<<dim3(16, 4, CCLS), blk, 0, stream>>>(
        x, wpk1, bs[0], nullptr, nullptr, nullptr, nullptr,
        gendata, ps1, pq1, 512, 0);

    // G2: bn1(h1)->relu -> h2[256], stats -> ps2 (nbtOut=16)
    gemm4_kernel<128, 512, true, true><<<dim3(16, 2, CCLS), blk, 0, stream>>>(
        gendata, wpk2, bs[1], ps1, pq1, g[0], be[0],
        h2, ps2, pq2, 256, 16);

    // G3: bn2(h2)->relu -> h3[128], stats -> ps3 (BM=64, nbtOut=32)
    gemm4_kernel<64, 256, true, true><<<dim3(32, 1, CCLS), blk, 0, stream>>>(
        h2, wpk3, bs[2], ps2, pq2, g[1], be[1],
        h3, ps3, pq3, 128, 16);

    // G4: bn3(h3)->relu -> h4[256] (aliases h2), stats -> ps4 (nbtOut=16)
    gemm4_kernel<128, 128, true, true><<<dim3(16, 2, CCLS), blk, 0, stream>>>(
        h3, wpk4, bs[3], ps3, pq3, g[2], be[2],
        h4, ps4, pq4, 256, 32);

    // G5: bn4(h4)->relu -> gendata[512] (no stats)
    gemm4_kernel<128, 256, true, false><<<dim3(16, 4, CCLS), blk, 0, stream>>>(
        h4, wpk5, bs[4], ps4, pq4, g[3], be[3],
        gendata, nullptr, nullptr, 512, 16);

    label_kernel<<<dim3(CCLS * BB / 256), blk, 0, stream>>>(label);
}